// Round 6
// baseline (1230.115 us; speedup 1.0000x reference)
//
#include <hip/hip_runtime.h>
#include <math.h>

#define N_NODES 100000
#define N_EDGES 3200000
#define SCAN_NB ((N_NODES + 255) / 256)   // 391
#define PLANE 800000                      // floats per feature-half plane (N*8)
#define X_FLOATS (N_NODES * 131)          // 13,100,000

// Sharded scatter: 8 dst-shards (one per XCD via blockIdx%8 round-robin heuristic)
#define N_SHARDS 8
#define NODES_PER_SHARD (N_NODES / N_SHARDS)   // 12500
#define N_CHUNKS 800
#define EDGES_PER_CHUNK (N_EDGES / N_CHUNKS)   // 4000

// MLP pass A tiling
#define TILE_NODES 128
#define MLP1_NB ((N_NODES + TILE_NODES - 1) / TILE_NODES)   // 782

// ---------------- CSR build ----------------

__global__ void k_init(int* __restrict__ count) {
    int i = blockIdx.x * blockDim.x + threadIdx.x;
    if (i < N_NODES) count[i] = 0;
}

__global__ void k_hist(const int* __restrict__ dst, int* __restrict__ count) {
    int e = blockIdx.x * blockDim.x + threadIdx.x;   // grid sized exactly E
    int d = __builtin_nontemporal_load(&dst[e]);
    atomicAdd(&count[d], 1);
}

__global__ __launch_bounds__(256) void k_scan1(const int* __restrict__ count,
                                               int* __restrict__ row_start,
                                               int* __restrict__ bsum) {
    __shared__ int tmp[256];
    const int t = threadIdx.x;
    const int i = blockIdx.x * 256 + t;
    int v = (i < N_NODES) ? count[i] : 0;
    tmp[t] = v;
    __syncthreads();
    for (int off = 1; off < 256; off <<= 1) {
        int a = (t >= off) ? tmp[t - off] : 0;
        __syncthreads();
        tmp[t] += a;
        __syncthreads();
    }
    if (i < N_NODES) row_start[i] = tmp[t] - v;   // exclusive
    if (t == 255) bsum[blockIdx.x] = tmp[255];
}

__global__ __launch_bounds__(512) void k_scan2(int* __restrict__ bsum) {
    __shared__ int tmp[512];
    const int t = threadIdx.x;
    int v = (t < SCAN_NB) ? bsum[t] : 0;
    tmp[t] = v;
    __syncthreads();
    for (int off = 1; off < 512; off <<= 1) {
        int a = (t >= off) ? tmp[t - off] : 0;
        __syncthreads();
        tmp[t] += a;
        __syncthreads();
    }
    if (t < SCAN_NB) bsum[t] = tmp[t] - v;   // exclusive
}

__global__ __launch_bounds__(256) void k_scan3(const int* __restrict__ count,
                                               int* __restrict__ row_start,
                                               const int* __restrict__ bsum,
                                               int* __restrict__ cursor,
                                               float* __restrict__ dinv) {
    const int i = blockIdx.x * 256 + threadIdx.x;
    if (i >= N_NODES) return;
    int rs = row_start[i] + bsum[blockIdx.x];
    row_start[i] = rs;
    cursor[i] = rs;
    dinv[i] = 1.0f / sqrtf((float)(count[i] + 1));   // deg includes self-loop
}

__global__ __launch_bounds__(256) void k_scatter(const int* __restrict__ src,
                                                 const int* __restrict__ dst,
                                                 int* __restrict__ cursor,
                                                 int* __restrict__ csr_src) {
    const int shard = blockIdx.x & (N_SHARDS - 1);
    const int chunk = blockIdx.x >> 3;
    const int lo = shard * NODES_PER_SHARD;
    const int hi = lo + NODES_PER_SHARD;
    const int e0 = chunk * EDGES_PER_CHUNK;
    const int e1 = e0 + EDGES_PER_CHUNK;
    for (int e = e0 + threadIdx.x; e < e1; e += 256) {
        int d = __builtin_nontemporal_load(&dst[e]);
        if (d >= lo && d < hi) {
            int s = __builtin_nontemporal_load(&src[e]);
            int pos = atomicAdd(&cursor[d], 1);
            csr_src[pos] = s;
        }
    }
}

// ---------------- MLP pass A: layer 1 (131 -> 64), x staged in LDS ----------------
// 128-node tile staged as-is (row stride 131 floats, odd -> 2-way bank aliasing =
// free). Staging copy is float4-coalesced. Two chunks of 32 accumulators (no
// spill). Weights block-uniform -> scalar loads. Output feature-major h1T[j][node]
// (64 coalesced write streams).

__global__ __launch_bounds__(128) void k_mlp1(
        const float* __restrict__ x,
        const float* __restrict__ W1, const float* __restrict__ b1,
        float* __restrict__ h1T) {
    __shared__ float xs[TILE_NODES * 131];   // 67072 B
    const int t = threadIdx.x;
    const int nbase = blockIdx.x * TILE_NODES;

    // stage tile (global layout == LDS layout -> straight coalesced copy)
    {
        const float4* xg = reinterpret_cast<const float4*>(x);
        float4* xl = reinterpret_cast<float4*>(xs);
        const int base4 = nbase * 131 / 4;            // tile base is 16B-aligned
        for (int i = t; i < TILE_NODES * 131 / 4; i += TILE_NODES) {
            int g = base4 + i;
            if (4 * g + 3 < X_FLOATS) xl[i] = xg[g];
        }
        // tail floats of the tile (131*128 divisible by 4 -> none), nothing to do
    }
    __syncthreads();

    const int node = nbase + t;
    if (node >= N_NODES) return;
    const float* myrow = xs + t * 131;

#pragma unroll
    for (int c = 0; c < 2; ++c) {
        float a[32];
#pragma unroll
        for (int j = 0; j < 32; ++j) a[j] = b1[c * 32 + j];
        for (int k = 0; k < 131; ++k) {
            float xk = myrow[k];
            const float* wr = W1 + k * 64 + c * 32;   // block-uniform -> s_load
#pragma unroll
            for (int j = 0; j < 32; ++j) a[j] += xk * wr[j];
        }
#pragma unroll
        for (int j = 0; j < 32; ++j)
            h1T[(c * 32 + j) * N_NODES + node] = tanhf(a[j]);
    }
}

// ---------------- MLP pass B: 64 -> 32 -> 16 -> conv-fuse ----------------
// Thread-per-node; h1T read feature-major -> every load coalesced; no LDS.
// Writes u0 planes: up[half*PLANE + node*8 + f] = (h3 @ Wc1)[f'] * dinv.

__global__ __launch_bounds__(256) void k_mlp2(
        const float* __restrict__ h1T,
        const float* __restrict__ W2, const float* __restrict__ b2,
        const float* __restrict__ W3, const float* __restrict__ b3,
        const float* __restrict__ Wc1,
        const float* __restrict__ dinv,
        float* __restrict__ up) {
    const int node = blockIdx.x * 256 + threadIdx.x;
    if (node >= N_NODES) return;

    float a2[32];
#pragma unroll
    for (int j = 0; j < 32; ++j) a2[j] = b2[j];
    for (int k = 0; k < 64; ++k) {
        float hk = h1T[k * N_NODES + node];           // coalesced
        const float* wr = W2 + k * 32;                // uniform -> s_load
#pragma unroll
        for (int j = 0; j < 32; ++j) a2[j] += hk * wr[j];
    }
#pragma unroll
    for (int j = 0; j < 32; ++j) a2[j] = tanhf(a2[j]);

    float a3[16];
#pragma unroll
    for (int j = 0; j < 16; ++j) a3[j] = b3[j];
#pragma unroll 4
    for (int k = 0; k < 32; ++k) {
        float hk = a2[k];
        const float* wr = W3 + k * 16;
#pragma unroll
        for (int j = 0; j < 16; ++j) a3[j] += hk * wr[j];
    }

    float dv = dinv[node];
    float uo[16];
#pragma unroll
    for (int j = 0; j < 16; ++j) uo[j] = 0.0f;
#pragma unroll 4
    for (int k = 0; k < 16; ++k) {
        float hk = a3[k];
        const float* wr = Wc1 + k * 16;
#pragma unroll
        for (int j = 0; j < 16; ++j) uo[j] += hk * wr[j];
    }
    float4* p0 = reinterpret_cast<float4*>(up + (long)node * 8);
    float4* p1 = reinterpret_cast<float4*>(up + PLANE + (long)node * 8);
    float4 v;
    v.x = uo[0] * dv; v.y = uo[1] * dv; v.z = uo[2] * dv; v.w = uo[3] * dv; p0[0] = v;
    v.x = uo[4] * dv; v.y = uo[5] * dv; v.z = uo[6] * dv; v.w = uo[7] * dv; p0[1] = v;
    v.x = uo[8] * dv; v.y = uo[9] * dv; v.z = uo[10] * dv; v.w = uo[11] * dv; p1[0] = v;
    v.x = uo[12] * dv; v.y = uo[13] * dv; v.z = uo[14] * dv; v.w = uo[15] * dv; p1[1] = v;
}

// ---------------- Aggregation over one feature-half plane ----------------

__global__ __launch_bounds__(256) void k_aggh(
        const float* __restrict__ up,
        const int* __restrict__ row_start,
        const int* __restrict__ count,
        const int* __restrict__ csr_src,
        const float* __restrict__ dinv,
        const float* __restrict__ bias,
        float* __restrict__ hp) {
    const int shard = blockIdx.x & 7;
    const int half = shard & 1;
    const int quarter = shard >> 1;
    const int wave = threadIdx.x >> 6;
    const int lane = threadIdx.x & 63;
    const int f = lane & 7;
    const int grp = (lane >> 3) & 3;
    const int nsel = lane >> 5;
    const int node = quarter * 25000 + (blockIdx.x >> 3) * 8 + wave * 2 + nsel;

    const float* u = up + half * PLANE;
    const int rs = row_start[node];
    const int cnt = count[node];
    const float dv = dinv[node];

    int cmax = max(cnt, __shfl_xor(cnt, 32, 64));   // wave-uniform loop bound

    float acc = 0.0f;
    for (int base = 0; base < cmax; base += 32) {
        int idx = csr_src[rs + base + (lane & 31)];
#pragma unroll
        for (int k = 0; k < 8; ++k) {
            int e = base + 4 * k + grp;
            int s = __shfl(idx, (lane & 32) + 4 * k + grp, 64);
            if (e < cnt) acc += u[s * 8 + f];
        }
    }
    acc += __shfl_xor(acc, 8, 64);
    acc += __shfl_xor(acc, 16, 64);
    acc += u[node * 8 + f];                 // self-loop (u already dinv[src]-scaled)

    float hn = tanhf(dv * acc + bias[half * 8 + f]);
    if (grp == 0) hp[half * PLANE + node * 8 + f] = hn;
}

// ---------------- Per-node 16x16 transform (full feature rows) ----------------

__global__ __launch_bounds__(256) void k_trans(
        const float* __restrict__ hp,
        const float* __restrict__ dinv,
        const float* __restrict__ W,
        const float* __restrict__ bcls,
        float* __restrict__ up_next,
        float* __restrict__ out,
        int mode) {
    int node = blockIdx.x * 256 + threadIdx.x;
    if (node >= N_NODES) return;

    const float4* p0 = reinterpret_cast<const float4*>(hp + (long)node * 8);
    const float4* p1 = reinterpret_cast<const float4*>(hp + PLANE + (long)node * 8);
    float4 ha = p0[0], hb = p0[1], hc = p1[0], hd = p1[1];
    float h[16] = {ha.x, ha.y, ha.z, ha.w, hb.x, hb.y, hb.z, hb.w,
                   hc.x, hc.y, hc.z, hc.w, hd.x, hd.y, hd.z, hd.w};

    if (mode == 0) {
        float dv = dinv[node];
        float o[16];
#pragma unroll
        for (int j = 0; j < 16; ++j) o[j] = 0.0f;
#pragma unroll 4
        for (int k = 0; k < 16; ++k) {
            float hk = h[k];
#pragma unroll
            for (int j = 0; j < 16; ++j) o[j] += hk * W[k * 16 + j];
        }
        float4* q0 = reinterpret_cast<float4*>(up_next + (long)node * 8);
        float4* q1 = reinterpret_cast<float4*>(up_next + PLANE + (long)node * 8);
        float4 v;
        v.x = o[0] * dv; v.y = o[1] * dv; v.z = o[2] * dv; v.w = o[3] * dv; q0[0] = v;
        v.x = o[4] * dv; v.y = o[5] * dv; v.z = o[6] * dv; v.w = o[7] * dv; q0[1] = v;
        v.x = o[8] * dv; v.y = o[9] * dv; v.z = o[10] * dv; v.w = o[11] * dv; q1[0] = v;
        v.x = o[12] * dv; v.y = o[13] * dv; v.z = o[14] * dv; v.w = o[15] * dv; q1[1] = v;
    } else {
        float c0 = bcls[0], c1 = bcls[1];
#pragma unroll
        for (int k = 0; k < 16; ++k) {
            c0 += h[k] * W[k * 2 + 0];
            c1 += h[k] * W[k * 2 + 1];
        }
        out[(long)node * 2 + 0] = c0;
        out[(long)node * 2 + 1] = c1;
        float4* ho = reinterpret_cast<float4*>(out + 200000 + (long)node * 16);
        ho[0] = ha; ho[1] = hb; ho[2] = hc; ho[3] = hd;
    }
}

// ---------------- launch ----------------

extern "C" void kernel_launch(void* const* d_in, const int* in_sizes, int n_in,
                              void* d_out, int out_size, void* d_ws, size_t ws_size,
                              hipStream_t stream) {
    const float* x    = (const float*)d_in[0];
    const int*   ei   = (const int*)d_in[1];
    const float* W1   = (const float*)d_in[2];
    const float* b1   = (const float*)d_in[3];
    const float* W2   = (const float*)d_in[4];
    const float* b2   = (const float*)d_in[5];
    const float* W3   = (const float*)d_in[6];
    const float* b3   = (const float*)d_in[7];
    const float* Wc1  = (const float*)d_in[8];
    const float* bc1  = (const float*)d_in[9];
    const float* Wg   = (const float*)d_in[10];
    const float* bg   = (const float*)d_in[11];
    const float* Wcls = (const float*)d_in[12];
    const float* bcls = (const float*)d_in[13];
    float* out = (float*)d_out;

    const int* src = ei;
    const int* dst = ei + N_EDGES;

    int* count     = (int*)d_ws;
    int* cursor    = count + N_NODES;
    int* row_start = cursor + N_NODES;
    float* dinv    = (float*)(row_start + N_NODES);
    int* csr_src   = (int*)(dinv + N_NODES);
    float* u       = (float*)(csr_src + N_EDGES);   // 2 planes of N*8 floats
    float* hp      = u + 2 * PLANE;                 // 2 planes of N*8 floats
    float* h1T     = hp + 2 * PLANE;                // 64 * N floats (25.6 MB)
    int* bsum      = csr_src;   // consumed by k_scan3 before k_scatter writes

    k_init<<<(N_NODES + 255) / 256, 256, 0, stream>>>(count);
    k_hist<<<N_EDGES / 256, 256, 0, stream>>>(dst, count);
    k_scan1<<<SCAN_NB, 256, 0, stream>>>(count, row_start, bsum);
    k_scan2<<<1, 512, 0, stream>>>(bsum);
    k_scan3<<<SCAN_NB, 256, 0, stream>>>(count, row_start, bsum, cursor, dinv);
    k_scatter<<<N_CHUNKS * N_SHARDS, 256, 0, stream>>>(src, dst, cursor, csr_src);
    k_mlp1<<<MLP1_NB, TILE_NODES, 0, stream>>>(x, W1, b1, h1T);
    k_mlp2<<<SCAN_NB, 256, 0, stream>>>(h1T, W2, b2, W3, b3, Wc1, dinv, u);

    for (int j = 0; j < 10; ++j) {
        const float* bias = (j < 5) ? bc1 : (bg + (long)(j - 5) * 16);
        k_aggh<<<25000, 256, 0, stream>>>(u, row_start, count, csr_src, dinv, bias, hp);
        if (j < 9) {
            const float* Wn = (j < 4) ? Wc1 : (Wg + (long)(j - 4) * 256);
            k_trans<<<SCAN_NB, 256, 0, stream>>>(hp, dinv, Wn, nullptr, u, nullptr, 0);
        } else {
            k_trans<<<SCAN_NB, 256, 0, stream>>>(hp, dinv, Wcls, bcls, nullptr, out, 1);
        }
    }
}

// Round 7
// 1119.834 us; speedup vs baseline: 1.0985x; 1.0985x over previous
//
#include <hip/hip_runtime.h>
#include <math.h>

#define N_NODES 100000
#define N_EDGES 3200000
#define SCAN_NB ((N_NODES + 255) / 256)   // 391
#define PLANE 800000                      // floats per feature-half plane (N*8)
#define X_FLOATS (N_NODES * 131)          // 13,100,000

// Sharded scatter: 8 dst-shards (one per XCD via blockIdx%8 round-robin heuristic)
#define N_SHARDS 8
#define NODES_PER_SHARD (N_NODES / N_SHARDS)   // 12500
#define N_CHUNKS 800
#define EDGES_PER_CHUNK (N_EDGES / N_CHUNKS)   // 4000

// MLP pass A tiling: 128-node tile, k staged in 4 chunks of <=33
#define TILE_NODES 128
#define KCH 33
#define MLP1_NB ((N_NODES + TILE_NODES - 1) / TILE_NODES)   // 782

// ---------------- CSR build ----------------

__global__ void k_init(int* __restrict__ count) {
    int i = blockIdx.x * blockDim.x + threadIdx.x;
    if (i < N_NODES) count[i] = 0;
}

__global__ void k_hist(const int* __restrict__ dst, int* __restrict__ count) {
    int e = blockIdx.x * blockDim.x + threadIdx.x;   // grid sized exactly E
    int d = __builtin_nontemporal_load(&dst[e]);
    atomicAdd(&count[d], 1);
}

__global__ __launch_bounds__(256) void k_scan1(const int* __restrict__ count,
                                               int* __restrict__ row_start,
                                               int* __restrict__ bsum) {
    __shared__ int tmp[256];
    const int t = threadIdx.x;
    const int i = blockIdx.x * 256 + t;
    int v = (i < N_NODES) ? count[i] : 0;
    tmp[t] = v;
    __syncthreads();
    for (int off = 1; off < 256; off <<= 1) {
        int a = (t >= off) ? tmp[t - off] : 0;
        __syncthreads();
        tmp[t] += a;
        __syncthreads();
    }
    if (i < N_NODES) row_start[i] = tmp[t] - v;   // exclusive
    if (t == 255) bsum[blockIdx.x] = tmp[255];
}

__global__ __launch_bounds__(512) void k_scan2(int* __restrict__ bsum) {
    __shared__ int tmp[512];
    const int t = threadIdx.x;
    int v = (t < SCAN_NB) ? bsum[t] : 0;
    tmp[t] = v;
    __syncthreads();
    for (int off = 1; off < 512; off <<= 1) {
        int a = (t >= off) ? tmp[t - off] : 0;
        __syncthreads();
        tmp[t] += a;
        __syncthreads();
    }
    if (t < SCAN_NB) bsum[t] = tmp[t] - v;   // exclusive
}

__global__ __launch_bounds__(256) void k_scan3(const int* __restrict__ count,
                                               int* __restrict__ row_start,
                                               const int* __restrict__ bsum,
                                               int* __restrict__ cursor,
                                               float* __restrict__ dinv) {
    const int i = blockIdx.x * 256 + threadIdx.x;
    if (i >= N_NODES) return;
    int rs = row_start[i] + bsum[blockIdx.x];
    row_start[i] = rs;
    cursor[i] = rs;
    dinv[i] = 1.0f / sqrtf((float)(count[i] + 1));   // deg includes self-loop
}

__global__ __launch_bounds__(256) void k_scatter(const int* __restrict__ src,
                                                 const int* __restrict__ dst,
                                                 int* __restrict__ cursor,
                                                 int* __restrict__ csr_src) {
    const int shard = blockIdx.x & (N_SHARDS - 1);
    const int chunk = blockIdx.x >> 3;
    const int lo = shard * NODES_PER_SHARD;
    const int hi = lo + NODES_PER_SHARD;
    const int e0 = chunk * EDGES_PER_CHUNK;
    const int e1 = e0 + EDGES_PER_CHUNK;
    for (int e = e0 + threadIdx.x; e < e1; e += 256) {
        int d = __builtin_nontemporal_load(&dst[e]);
        if (d >= lo && d < hi) {
            int s = __builtin_nontemporal_load(&src[e]);
            int pos = atomicAdd(&cursor[d], 1);
            csr_src[pos] = s;
        }
    }
}

// ---------------- MLP pass A: layer 1 (131 -> 64), k-chunked LDS staging ----------------
// 256 threads / 128-node tile: thread half (t>>7, forced wave-uniform) owns 32 of
// the 64 outputs -> 32 accumulators/thread, no spill. x staged per k-chunk
// (128x33 = 16.9 KB) -> 8+ blocks/CU co-resident (R6's 67 KB tile gave 9%
// occupancy = latency death). Stride-33 LDS reads: 2-way bank aliasing = free.
// Weights via SGPR (uniform address). Output feature-major h1T[j][node], coalesced.

__global__ __launch_bounds__(256) void k_mlp1(
        const float* __restrict__ x,
        const float* __restrict__ W1, const float* __restrict__ b1,
        float* __restrict__ h1T) {
    __shared__ float xs[TILE_NODES * KCH];   // 16896 B
    const int t = threadIdx.x;
    const int nl = t & 127;
    const int half_u = __builtin_amdgcn_readfirstlane(t >> 7);  // wave-uniform
    const int nbase = blockIdx.x * TILE_NODES;
    const int node = nbase + nl;

    float a[32];
#pragma unroll
    for (int j = 0; j < 32; ++j) a[j] = b1[half_u * 32 + j];

    for (int kc = 0; kc < 4; ++kc) {
        const int k0 = kc * KCH;
        const int len = (k0 + KCH <= 131) ? KCH : (131 - k0);   // 33,33,33,32
        __syncthreads();
        // stage chunk: xs[r*33 + c] = x[(nbase+r)*131 + k0 + c]
        for (int i = t; i < TILE_NODES * KCH; i += 256) {
            int r = i / KCH;
            int c = i - r * KCH;
            int gr = nbase + r;
            xs[i] = (c < len && gr < N_NODES) ? x[(long)gr * 131 + k0 + c] : 0.0f;
        }
        __syncthreads();
        const float* myrow = xs + nl * KCH;
        for (int kk = 0; kk < len; ++kk) {
            float xk = myrow[kk];
            const float* wr = W1 + (k0 + kk) * 64 + half_u * 32;   // uniform -> s_load
#pragma unroll
            for (int j = 0; j < 32; ++j) a[j] += xk * wr[j];
        }
    }

    if (node < N_NODES) {
#pragma unroll
        for (int j = 0; j < 32; ++j)
            h1T[(half_u * 32 + j) * N_NODES + node] = tanhf(a[j]);
    }
}

// ---------------- MLP pass B: 64 -> 32 -> 16 -> conv-fuse ----------------

__global__ __launch_bounds__(256) void k_mlp2(
        const float* __restrict__ h1T,
        const float* __restrict__ W2, const float* __restrict__ b2,
        const float* __restrict__ W3, const float* __restrict__ b3,
        const float* __restrict__ Wc1,
        const float* __restrict__ dinv,
        float* __restrict__ up) {
    const int node = blockIdx.x * 256 + threadIdx.x;
    if (node >= N_NODES) return;

    float a2[32];
#pragma unroll
    for (int j = 0; j < 32; ++j) a2[j] = b2[j];
    for (int k = 0; k < 64; ++k) {
        float hk = h1T[k * N_NODES + node];           // coalesced
        const float* wr = W2 + k * 32;                // uniform -> s_load
#pragma unroll
        for (int j = 0; j < 32; ++j) a2[j] += hk * wr[j];
    }
#pragma unroll
    for (int j = 0; j < 32; ++j) a2[j] = tanhf(a2[j]);

    float a3[16];
#pragma unroll
    for (int j = 0; j < 16; ++j) a3[j] = b3[j];
#pragma unroll 4
    for (int k = 0; k < 32; ++k) {
        float hk = a2[k];
        const float* wr = W3 + k * 16;
#pragma unroll
        for (int j = 0; j < 16; ++j) a3[j] += hk * wr[j];
    }

    float dv = dinv[node];
    float uo[16];
#pragma unroll
    for (int j = 0; j < 16; ++j) uo[j] = 0.0f;
#pragma unroll 4
    for (int k = 0; k < 16; ++k) {
        float hk = a3[k];
        const float* wr = Wc1 + k * 16;
#pragma unroll
        for (int j = 0; j < 16; ++j) uo[j] += hk * wr[j];
    }
    float4* p0 = reinterpret_cast<float4*>(up + (long)node * 8);
    float4* p1 = reinterpret_cast<float4*>(up + PLANE + (long)node * 8);
    float4 v;
    v.x = uo[0] * dv; v.y = uo[1] * dv; v.z = uo[2] * dv; v.w = uo[3] * dv; p0[0] = v;
    v.x = uo[4] * dv; v.y = uo[5] * dv; v.z = uo[6] * dv; v.w = uo[7] * dv; p0[1] = v;
    v.x = uo[8] * dv; v.y = uo[9] * dv; v.z = uo[10] * dv; v.w = uo[11] * dv; p1[0] = v;
    v.x = uo[12] * dv; v.y = uo[13] * dv; v.z = uo[14] * dv; v.w = uo[15] * dv; p1[1] = v;
}

// ---------------- Aggregation over one feature-half plane ----------------

__global__ __launch_bounds__(256) void k_aggh(
        const float* __restrict__ up,
        const int* __restrict__ row_start,
        const int* __restrict__ count,
        const int* __restrict__ csr_src,
        const float* __restrict__ dinv,
        const float* __restrict__ bias,
        float* __restrict__ hp) {
    const int shard = blockIdx.x & 7;
    const int half = shard & 1;
    const int quarter = shard >> 1;
    const int wave = threadIdx.x >> 6;
    const int lane = threadIdx.x & 63;
    const int f = lane & 7;
    const int grp = (lane >> 3) & 3;
    const int nsel = lane >> 5;
    const int node = quarter * 25000 + (blockIdx.x >> 3) * 8 + wave * 2 + nsel;

    const float* u = up + half * PLANE;
    const int rs = row_start[node];
    const int cnt = count[node];
    const float dv = dinv[node];

    int cmax = max(cnt, __shfl_xor(cnt, 32, 64));   // wave-uniform loop bound

    float acc = 0.0f;
    for (int base = 0; base < cmax; base += 32) {
        int idx = csr_src[rs + base + (lane & 31)];
#pragma unroll
        for (int k = 0; k < 8; ++k) {
            int e = base + 4 * k + grp;
            int s = __shfl(idx, (lane & 32) + 4 * k + grp, 64);
            if (e < cnt) acc += u[s * 8 + f];
        }
    }
    acc += __shfl_xor(acc, 8, 64);
    acc += __shfl_xor(acc, 16, 64);
    acc += u[node * 8 + f];                 // self-loop (u already dinv[src]-scaled)

    float hn = tanhf(dv * acc + bias[half * 8 + f]);
    if (grp == 0) hp[half * PLANE + node * 8 + f] = hn;
}

// ---------------- Per-node 16x16 transform (full feature rows) ----------------

__global__ __launch_bounds__(256) void k_trans(
        const float* __restrict__ hp,
        const float* __restrict__ dinv,
        const float* __restrict__ W,
        const float* __restrict__ bcls,
        float* __restrict__ up_next,
        float* __restrict__ out,
        int mode) {
    int node = blockIdx.x * 256 + threadIdx.x;
    if (node >= N_NODES) return;

    const float4* p0 = reinterpret_cast<const float4*>(hp + (long)node * 8);
    const float4* p1 = reinterpret_cast<const float4*>(hp + PLANE + (long)node * 8);
    float4 ha = p0[0], hb = p0[1], hc = p1[0], hd = p1[1];
    float h[16] = {ha.x, ha.y, ha.z, ha.w, hb.x, hb.y, hb.z, hb.w,
                   hc.x, hc.y, hc.z, hc.w, hd.x, hd.y, hd.z, hd.w};

    if (mode == 0) {
        float dv = dinv[node];
        float o[16];
#pragma unroll
        for (int j = 0; j < 16; ++j) o[j] = 0.0f;
#pragma unroll 4
        for (int k = 0; k < 16; ++k) {
            float hk = h[k];
#pragma unroll
            for (int j = 0; j < 16; ++j) o[j] += hk * W[k * 16 + j];
        }
        float4* q0 = reinterpret_cast<float4*>(up_next + (long)node * 8);
        float4* q1 = reinterpret_cast<float4*>(up_next + PLANE + (long)node * 8);
        float4 v;
        v.x = o[0] * dv; v.y = o[1] * dv; v.z = o[2] * dv; v.w = o[3] * dv; q0[0] = v;
        v.x = o[4] * dv; v.y = o[5] * dv; v.z = o[6] * dv; v.w = o[7] * dv; q0[1] = v;
        v.x = o[8] * dv; v.y = o[9] * dv; v.z = o[10] * dv; v.w = o[11] * dv; q1[0] = v;
        v.x = o[12] * dv; v.y = o[13] * dv; v.z = o[14] * dv; v.w = o[15] * dv; q1[1] = v;
    } else {
        float c0 = bcls[0], c1 = bcls[1];
#pragma unroll
        for (int k = 0; k < 16; ++k) {
            c0 += h[k] * W[k * 2 + 0];
            c1 += h[k] * W[k * 2 + 1];
        }
        out[(long)node * 2 + 0] = c0;
        out[(long)node * 2 + 1] = c1;
        float4* ho = reinterpret_cast<float4*>(out + 200000 + (long)node * 16);
        ho[0] = ha; ho[1] = hb; ho[2] = hc; ho[3] = hd;
    }
}

// ---------------- launch ----------------

extern "C" void kernel_launch(void* const* d_in, const int* in_sizes, int n_in,
                              void* d_out, int out_size, void* d_ws, size_t ws_size,
                              hipStream_t stream) {
    const float* x    = (const float*)d_in[0];
    const int*   ei   = (const int*)d_in[1];
    const float* W1   = (const float*)d_in[2];
    const float* b1   = (const float*)d_in[3];
    const float* W2   = (const float*)d_in[4];
    const float* b2   = (const float*)d_in[5];
    const float* W3   = (const float*)d_in[6];
    const float* b3   = (const float*)d_in[7];
    const float* Wc1  = (const float*)d_in[8];
    const float* bc1  = (const float*)d_in[9];
    const float* Wg   = (const float*)d_in[10];
    const float* bg   = (const float*)d_in[11];
    const float* Wcls = (const float*)d_in[12];
    const float* bcls = (const float*)d_in[13];
    float* out = (float*)d_out;

    const int* src = ei;
    const int* dst = ei + N_EDGES;

    int* count     = (int*)d_ws;
    int* cursor    = count + N_NODES;
    int* row_start = cursor + N_NODES;
    float* dinv    = (float*)(row_start + N_NODES);
    int* csr_src   = (int*)(dinv + N_NODES);
    float* u       = (float*)(csr_src + N_EDGES);   // 2 planes of N*8 floats
    float* hp      = u + 2 * PLANE;                 // 2 planes of N*8 floats
    float* h1T     = hp + 2 * PLANE;                // 64 * N floats (25.6 MB)
    int* bsum      = csr_src;   // consumed by k_scan3 before k_scatter writes

    k_init<<<(N_NODES + 255) / 256, 256, 0, stream>>>(count);
    k_hist<<<N_EDGES / 256, 256, 0, stream>>>(dst, count);
    k_scan1<<<SCAN_NB, 256, 0, stream>>>(count, row_start, bsum);
    k_scan2<<<1, 512, 0, stream>>>(bsum);
    k_scan3<<<SCAN_NB, 256, 0, stream>>>(count, row_start, bsum, cursor, dinv);
    k_scatter<<<N_CHUNKS * N_SHARDS, 256, 0, stream>>>(src, dst, cursor, csr_src);
    k_mlp1<<<MLP1_NB, 256, 0, stream>>>(x, W1, b1, h1T);
    k_mlp2<<<SCAN_NB, 256, 0, stream>>>(h1T, W2, b2, W3, b3, Wc1, dinv, u);

    for (int j = 0; j < 10; ++j) {
        const float* bias = (j < 5) ? bc1 : (bg + (long)(j - 5) * 16);
        k_aggh<<<25000, 256, 0, stream>>>(u, row_start, count, csr_src, dinv, bias, hp);
        if (j < 9) {
            const float* Wn = (j < 4) ? Wc1 : (Wg + (long)(j - 4) * 256);
            k_trans<<<SCAN_NB, 256, 0, stream>>>(hp, dinv, Wn, nullptr, u, nullptr, 0);
        } else {
            k_trans<<<SCAN_NB, 256, 0, stream>>>(hp, dinv, Wcls, bcls, nullptr, out, 1);
        }
    }
}